// Round 13
// baseline (126.737 us; speedup 1.0000x reference)
//
#include <hip/hip_runtime.h>
#include <cstdint>
#include <cstddef>

#define TPB 256
#define PTPB 1024  // prehist: 256 nodes/block -> 196 blocks (one round)
#define QTPB 512   // post: 128 nodes/block -> 391 blocks at 2/CU (one round)
#define LPAD 136   // shorts per LDS row (272 B, 16B-aligned stride)
#define CAP 48     // per-node edge bucket capacity (Poisson(12): P(>=48)~1e-15)

using frag_ab = __attribute__((ext_vector_type(8))) short;  // 8 bf16
using f32x4   = __attribute__((ext_vector_type(4))) float;  // 4 fp32 acc
using u16x4   = __attribute__((ext_vector_type(4))) ushort; // 4 bf16 (8B)

__device__ inline ushort f2b(float f) {
    uint u = __builtin_bit_cast(uint, f);
    u = (u + 0x7FFFu + ((u >> 16) & 1u)) >> 16;
    return (ushort)u;
}
__device__ inline float b2f_lo(uint u) { return __builtin_bit_cast(float, u << 16); }
__device__ inline float b2f_hi(uint u) { return __builtin_bit_cast(float, u & 0xFFFF0000u); }

// ---------------------------------------------------------------------------
// pack: fp32 [128][128] weight -> bf16 fragment order (A-operand of swapped
// product) + zero the degree counters.
// ---------------------------------------------------------------------------
__global__ __launch_bounds__(TPB) void pack_kernel(
    const float* __restrict__ h_w1, const float* __restrict__ f_w,
    const float* __restrict__ g_w1, const float* __restrict__ g_w2,
    short* __restrict__ W1pk, short* __restrict__ Wfpk,
    short* __restrict__ G1pk, short* __restrict__ G2pk,
    int* __restrict__ deg, int M)
{
    int m   = blockIdx.y;
    int fid = blockIdx.x * TPB + threadIdx.x;     // 0..2047
    int lane = fid & 63, ks = (fid >> 6) & 3, nt = fid >> 8;
    const float* src; short* dst; int rowoff = 0;
    if      (m == 0) { src = h_w1; dst = W1pk; }
    else if (m == 1) { src = f_w;  dst = Wfpk; rowoff = 3; }
    else if (m == 2) { src = g_w1; dst = G1pk; }
    else             { src = g_w2; dst = G2pk; }
    int col   = nt * 16 + (lane & 15);
    int kbase = ks * 32 + ((lane >> 4) << 3);
    frag_ab f;
#pragma unroll
    for (int j = 0; j < 8; ++j)
        f[j] = (short)f2b(src[(size_t)(rowoff + kbase + j) * 128 + col]);
    *(frag_ab*)(dst + (((size_t)(nt * 4 + ks) * 64 + lane) << 3)) = f;

    // zero deg: grid-stride
    int flat = (blockIdx.y * gridDim.x + blockIdx.x) * TPB + threadIdx.x;
    int nthr = gridDim.y * gridDim.x * TPB;
    for (int i = flat; i < M; i += nthr) deg[i] = 0;
}

// ---------------------------------------------------------------------------
// prehist: FUSED padded-bucket edge scatter (hoisted to the FRONT so its
// atomic/store latency drains under the node phase) + node phase.
// 1024 threads, 256 nodes/block -> 196 blocks, one round.
// ---------------------------------------------------------------------------
__global__ __launch_bounds__(PTPB) void prehist_kernel(
    const float* __restrict__ x, const float* __restrict__ pos,
    const short* __restrict__ W1pk,   // Wfpk contiguous at +16384
    const float* __restrict__ h_b1,
    const float* __restrict__ h_w2, const float* __restrict__ h_b2,
    const float* __restrict__ f_w, const float* __restrict__ f_b,
    ushort* __restrict__ A2h, ushort* __restrict__ Bvh,
    const int* __restrict__ ei, int* __restrict__ deg,
    int* __restrict__ sspad, int M, int E, int echunk)
{
    __shared__ short wlds[32768];     // 64 KB: W1pk | Wfpk
    const int tid  = threadIdx.x;
    const int lane = tid & 63;
    const int wave = tid >> 6;        // 0..15
    const int kg   = lane >> 4;
    const int node = blockIdx.x * 256 + wave * 16 + (lane & 15);
    const int nc   = node < M ? node : M - 1;

    // issue x + pos loads first (longest latency)
    float4 xv0[4], xv1[4];
#pragma unroll
    for (int ks = 0; ks < 4; ++ks) {
        const float* px = x + (size_t)nc * 128 + ks * 32 + kg * 8;
        xv0[ks] = *(const float4*)px;
        xv1[ks] = *(const float4*)(px + 4);
    }
    float p0 = pos[(size_t)nc * 3 + 0];
    float p1 = pos[(size_t)nc * 3 + 1];
    float p2 = pos[(size_t)nc * 3 + 2];

    // padded-bucket scatter FIRST: its atomics + scattered stores drain
    // under the whole node phase below (no dependency between them).
    {
        int base = blockIdx.x * echunk;
        int end  = base + echunk; if (end > E) end = E;
        for (int i = base + tid; i < end; i += PTPB) {
            int s = ei[i];
            int d = ei[E + i];
            int p = atomicAdd(&deg[d], 1);
            if (p < CAP) sspad[d * CAP + p] = s;
        }
    }

    // stage both weight matrices (contiguous): 4096 int4s / 1024 thr
#pragma unroll
    for (int i = 0; i < 4; ++i) {
        int id = i * PTPB + tid;
        *(int4*)(wlds + (size_t)id * 8) = *(const int4*)(W1pk + (size_t)id * 8);
    }

    // convert x to bf16 fragments while staging lands
    frag_ab xb[4];
#pragma unroll
    for (int ks = 0; ks < 4; ++ks) {
        frag_ab f;
        f[0] = (short)f2b(xv0[ks].x); f[1] = (short)f2b(xv0[ks].y);
        f[2] = (short)f2b(xv0[ks].z); f[3] = (short)f2b(xv0[ks].w);
        f[4] = (short)f2b(xv1[ks].x); f[5] = (short)f2b(xv1[ks].y);
        f[6] = (short)f2b(xv1[ks].z); f[7] = (short)f2b(xv1[ks].w);
        xb[ks] = f;
    }
    __syncthreads();

    f32x4 acch[8], acca[8];
#pragma unroll
    for (int nt = 0; nt < 8; ++nt) { acch[nt] = (f32x4)0.f; acca[nt] = (f32x4)0.f; }
#pragma unroll
    for (int ks = 0; ks < 4; ++ks) {
#pragma unroll
        for (int nt = 0; nt < 8; ++nt) {
            frag_ab wh = *(const frag_ab*)(wlds + (((nt * 4 + ks) * 64 + lane) << 3));
            acch[nt] = __builtin_amdgcn_mfma_f32_16x16x32_bf16(wh, xb[ks], acch[nt], 0, 0, 0);
            frag_ab wf = *(const frag_ab*)(wlds + 16384 + (((nt * 4 + ks) * 64 + lane) << 3));
            acca[nt] = __builtin_amdgcn_mfma_f32_16x16x32_bf16(wf, xb[ks], acca[nt], 0, 0, 0);
        }
    }

    // delta head
    float d0 = 0.f, d1 = 0.f, d2 = 0.f;
#pragma unroll
    for (int nt = 0; nt < 8; ++nt) {
        int f0 = nt * 16 + kg * 4;
        float4 b1 = *(const float4*)(h_b1 + f0);
        float w2[12];
        *(float4*)(w2 + 0) = *(const float4*)(h_w2 + f0 * 3);
        *(float4*)(w2 + 4) = *(const float4*)(h_w2 + f0 * 3 + 4);
        *(float4*)(w2 + 8) = *(const float4*)(h_w2 + f0 * 3 + 8);
#pragma unroll
        for (int j = 0; j < 4; ++j) {
            float h = fmaxf(acch[nt][j] + ((const float*)&b1)[j], 0.f);
            d0 += h * w2[j * 3 + 0];
            d1 += h * w2[j * 3 + 1];
            d2 += h * w2[j * 3 + 2];
        }
    }
    d0 += __shfl_xor(d0, 16); d0 += __shfl_xor(d0, 32);
    d1 += __shfl_xor(d1, 16); d1 += __shfl_xor(d1, 32);
    d2 += __shfl_xor(d2, 16); d2 += __shfl_xor(d2, 32);
    d0 = tanhf(d0 + h_b2[0]);
    d1 = tanhf(d1 + h_b2[1]);
    d2 = tanhf(d2 + h_b2[2]);

    if (node < M) {
#pragma unroll
        for (int nt = 0; nt < 8; ++nt) {
            int f0 = nt * 16 + kg * 4;
            float4 w0 = *(const float4*)(f_w + f0);
            float4 w1 = *(const float4*)(f_w + 128 + f0);
            float4 w2 = *(const float4*)(f_w + 256 + f0);
            float4 fb = *(const float4*)(f_b + f0);
            u16x4 av, bv;
#pragma unroll
            for (int j = 0; j < 4; ++j) {
                float ww0 = ((const float*)&w0)[j];
                float ww1 = ((const float*)&w1)[j];
                float ww2 = ((const float*)&w2)[j];
                float pw = p0 * ww0 + p1 * ww1 + p2 * ww2;
                float dw = d0 * ww0 + d1 * ww1 + d2 * ww2;
                av[j] = f2b(acca[nt][j] + pw);
                bv[j] = f2b(((const float*)&fb)[j] + dw - pw);
            }
            *(u16x4*)(A2h + (size_t)node * 128 + f0) = av;
            *(u16x4*)(Bvh + (size_t)node * 128 + f0) = bv;
        }
    }
}

// ---------------------------------------------------------------------------
// segmented reduce over padded buckets: one wave per row, two 32-lane halves
// process alternate edges; bucket indices fetched 4-at-a-time (wave-uniform
// int4 -> scalar loads). __shfl_xor(32) combines. bf16 output.
// ---------------------------------------------------------------------------
__global__ __launch_bounds__(TPB) void reduce_kernel(
    const int* __restrict__ deg, const int* __restrict__ sspad,
    const ushort* __restrict__ A2h, const ushort* __restrict__ Bvh,
    ushort* __restrict__ aggr, int M)
{
    int row = blockIdx.x * 4 + (threadIdx.x >> 6);
    if (row >= M) return;
    int lane = threadIdx.x & 63;
    int half = lane >> 5;
    int cl   = (lane & 31) * 4;

    uint2 bu = *(const uint2*)(Bvh + (size_t)row * 128 + cl);
    float b0 = b2f_lo(bu.x), b1 = b2f_hi(bu.x);
    float b2 = b2f_lo(bu.y), b3 = b2f_hi(bu.y);
    float a0 = 0.f, a1 = 0.f, a2 = 0.f, a3 = 0.f;

    const int* bkt = sspad + (size_t)row * CAP;
    int k1 = deg[row]; if (k1 > CAP) k1 = CAP;

    for (int kb = 0; kb < k1; kb += 4) {
        int4 ss = *(const int4*)(bkt + kb);   // wave-uniform, CAP%4==0: safe
        int rem = k1 - kb;                    // 1..4 on last iter
        if (half == 0) {
            {   // edge kb+0 (always valid)
                uint2 u = *(const uint2*)(A2h + (size_t)ss.x * 128 + cl);
                a0 += fmaxf(b2f_lo(u.x) + b0, 0.f);
                a1 += fmaxf(b2f_hi(u.x) + b1, 0.f);
                a2 += fmaxf(b2f_lo(u.y) + b2, 0.f);
                a3 += fmaxf(b2f_hi(u.y) + b3, 0.f);
            }
            if (rem > 2) {   // edge kb+2
                uint2 u = *(const uint2*)(A2h + (size_t)ss.z * 128 + cl);
                a0 += fmaxf(b2f_lo(u.x) + b0, 0.f);
                a1 += fmaxf(b2f_hi(u.x) + b1, 0.f);
                a2 += fmaxf(b2f_lo(u.y) + b2, 0.f);
                a3 += fmaxf(b2f_hi(u.y) + b3, 0.f);
            }
        } else {
            if (rem > 1) {   // edge kb+1
                uint2 u = *(const uint2*)(A2h + (size_t)ss.y * 128 + cl);
                a0 += fmaxf(b2f_lo(u.x) + b0, 0.f);
                a1 += fmaxf(b2f_hi(u.x) + b1, 0.f);
                a2 += fmaxf(b2f_lo(u.y) + b2, 0.f);
                a3 += fmaxf(b2f_hi(u.y) + b3, 0.f);
            }
            if (rem > 3) {   // edge kb+3
                uint2 u = *(const uint2*)(A2h + (size_t)ss.w * 128 + cl);
                a0 += fmaxf(b2f_lo(u.x) + b0, 0.f);
                a1 += fmaxf(b2f_hi(u.x) + b1, 0.f);
                a2 += fmaxf(b2f_lo(u.y) + b2, 0.f);
                a3 += fmaxf(b2f_hi(u.y) + b3, 0.f);
            }
        }
    }
    // combine halves
    a0 += __shfl_xor(a0, 32);
    a1 += __shfl_xor(a1, 32);
    a2 += __shfl_xor(a2, 32);
    a3 += __shfl_xor(a3, 32);

    if (half == 0) {
        uint2 r;
        r.x = (uint)f2b(a0) | ((uint)f2b(a1) << 16);
        r.y = (uint)f2b(a2) | ((uint)f2b(a3) << 16);
        *(uint2*)(aggr + (size_t)row * 128 + cl) = r;
    }
}

// ---------------------------------------------------------------------------
// post: out = relu(aggr@g_w1+g_b1)@g_w2 + g_b2 + x  via swapped MFMA.
// ---------------------------------------------------------------------------
__global__ __launch_bounds__(QTPB) void post_kernel(
    const float* __restrict__ x, const ushort* __restrict__ aggr,
    const short* __restrict__ G1pk, const float* __restrict__ g_b1,
    const short* __restrict__ G2pk, const float* __restrict__ g_b2,
    float* __restrict__ out, int M)
{
    __shared__ short glds[16384];           // 32 KB staged weight / out-bounce
    __shared__ short bounce[8 * 16 * LPAD]; // 34.8 KB
    const int tid  = threadIdx.x;
    const int lane = tid & 63;
    const int wave = tid >> 6;              // 0..7
    const int kg   = lane >> 4;
    short* ws = bounce + wave * 16 * LPAD;

    const int node = blockIdx.x * 128 + wave * 16 + (lane & 15);
    const int nc   = node < M ? node : M - 1;

    // B-fragments of aggr^T: direct 16B global loads (issue before staging)
    frag_ab ab[4];
#pragma unroll
    for (int ks = 0; ks < 4; ++ks)
        ab[ks] = *(const frag_ab*)(aggr + (size_t)nc * 128 + ks * 32 + kg * 8);

    // stage G1 (2048 int4s / 512 thr = 4 iters)
#pragma unroll
    for (int i = 0; i < 4; ++i) {
        int id = i * QTPB + tid;
        *(int4*)(glds + (size_t)id * 8) = *(const int4*)(G1pk + (size_t)id * 8);
    }
    __syncthreads();

    // GEMM1: hidden2^T
    f32x4 h2[8];
#pragma unroll
    for (int nt = 0; nt < 8; ++nt) h2[nt] = (f32x4)0.f;
#pragma unroll
    for (int ks = 0; ks < 4; ++ks) {
#pragma unroll
        for (int nt = 0; nt < 8; ++nt) {
            frag_ab g = *(const frag_ab*)(glds + (((nt * 4 + ks) * 64 + lane) << 3));
            h2[nt] = __builtin_amdgcn_mfma_f32_16x16x32_bf16(g, ab[ks], h2[nt], 0, 0, 0);
        }
    }
    // relu+bias -> bf16 -> wave-private LDS
#pragma unroll
    for (int nt = 0; nt < 8; ++nt) {
        int f0 = nt * 16 + kg * 4;
        float4 gb = *(const float4*)(g_b1 + f0);
        u16x4 hv;
#pragma unroll
        for (int j = 0; j < 4; ++j)
            hv[j] = f2b(fmaxf(h2[nt][j] + ((const float*)&gb)[j], 0.f));
        *(u16x4*)(ws + (lane & 15) * LPAD + f0) = hv;
    }
    __syncthreads();   // all waves done reading G1

    // stage G2 over the same buffer
#pragma unroll
    for (int i = 0; i < 4; ++i) {
        int id = i * QTPB + tid;
        *(int4*)(glds + (size_t)id * 8) = *(const int4*)(G2pk + (size_t)id * 8);
    }
    __syncthreads();

    // GEMM2: out^T
    f32x4 o[8];
#pragma unroll
    for (int nt = 0; nt < 8; ++nt) o[nt] = (f32x4)0.f;
#pragma unroll
    for (int ks = 0; ks < 4; ++ks) {
        frag_ab bfr = *(const frag_ab*)(ws + (lane & 15) * LPAD + ks * 32 + kg * 8);
#pragma unroll
        for (int nt = 0; nt < 8; ++nt) {
            frag_ab g = *(const frag_ab*)(glds + (((nt * 4 + ks) * 64 + lane) << 3));
            o[nt] = __builtin_amdgcn_mfma_f32_16x16x32_bf16(g, bfr, o[nt], 0, 0, 0);
        }
    }

    __syncthreads();   // all waves done reading G2: glds becomes out-bounce
    float* ob = (float*)glds + (wave << 10);   // 4 KB per wave
    const int nhalf = (lane & 15) >> 3;
#pragma unroll
    for (int p = 0; p < 2; ++p) {
        if (nhalf == p) {
            int ln = lane & 7;
#pragma unroll
            for (int nt = 0; nt < 8; ++nt) {
                float4 v;
                v.x = o[nt][0]; v.y = o[nt][1]; v.z = o[nt][2]; v.w = o[nt][3];
                *(float4*)(ob + ln * 128 + nt * 16 + kg * 4) = v;
            }
        }
#pragma unroll
        for (int it = 0; it < 4; ++it) {
            int ln2 = lane >> 3;           // 0..7
            int cc  = (lane & 7) + it * 8; // 0..31 (16B chunks)
            float4 v = *(const float4*)(ob + ln2 * 128 + cc * 4);
            int gn = blockIdx.x * 128 + wave * 16 + p * 8 + ln2;
            if (gn < M) {
                float4 xv = *(const float4*)(x + (size_t)gn * 128 + cc * 4);
                float4 gb = *(const float4*)(g_b2 + cc * 4);
                float4 ov;
                ov.x = v.x + gb.x + xv.x; ov.y = v.y + gb.y + xv.y;
                ov.z = v.z + gb.z + xv.z; ov.w = v.w + gb.w + xv.w;
                *(float4*)(out + (size_t)gn * 128 + cc * 4) = ov;
            }
        }
    }
}

extern "C" void kernel_launch(void* const* d_in, const int* in_sizes, int n_in,
                              void* d_out, int out_size, void* d_ws, size_t ws_size,
                              hipStream_t stream)
{
    const float* x    = (const float*)d_in[0];
    const float* pos  = (const float*)d_in[1];
    const int*   ei   = (const int*)d_in[2];
    const float* h_w1 = (const float*)d_in[3];
    const float* h_b1 = (const float*)d_in[4];
    const float* h_w2 = (const float*)d_in[5];
    const float* h_b2 = (const float*)d_in[6];
    const float* f_w  = (const float*)d_in[7];
    const float* f_b  = (const float*)d_in[8];
    const float* g_w1 = (const float*)d_in[9];
    const float* g_b1 = (const float*)d_in[10];
    const float* g_w2 = (const float*)d_in[11];
    const float* g_b2 = (const float*)d_in[12];

    const int M = in_sizes[1] / 3;       // 50000
    const int E = in_sizes[2] / 2;       // 600000
    const int nbp = (M + 255) / 256;     // 196 prehist blocks
    const int nbq = (M + 127) / 128;     // 391 post blocks
    const int echunk = (E + nbp - 1) / nbp;

    ushort* A2h  = (ushort*)d_ws;                          // [M][128] bf16
    ushort* Bvh  = A2h + (size_t)M * 128;                  // [M][128] bf16
    ushort* aggr = Bvh + (size_t)M * 128;                  // [M][128] bf16
    short* W1pk  = (short*)(aggr + (size_t)M * 128);       // 16384 each, W1|Wf contiguous
    short* Wfpk  = W1pk + 16384;
    short* G1pk  = Wfpk + 16384;
    short* G2pk  = G1pk + 16384;
    int* deg     = (int*)(G2pk + 16384);                   // [M]
    int* sspad   = deg + M;                                // [M*CAP]
    float* out   = (float*)d_out;

    pack_kernel<<<dim3(8, 4), TPB, 0, stream>>>(h_w1, f_w, g_w1, g_w2,
                                                W1pk, Wfpk, G1pk, G2pk,
                                                deg, M);
    prehist_kernel<<<nbp, PTPB, 0, stream>>>(x, pos, W1pk, h_b1, h_w2, h_b2,
                                             f_w, f_b, A2h, Bvh,
                                             ei, deg, sspad, M, E, echunk);
    reduce_kernel<<<(M + 3) / 4, TPB, 0, stream>>>(deg, sspad, A2h, Bvh, aggr, M);
    post_kernel<<<nbq, QTPB, 0, stream>>>(x, aggr, G1pk, g_b1, G2pk, g_b2, out, M);
}

// Round 14
// 96.029 us; speedup vs baseline: 1.3198x; 1.3198x over previous
//
#include <hip/hip_runtime.h>
#include <cstdint>
#include <cstddef>

#define TPB 256
#define PTPB 1024  // prehist: 256 nodes/block -> 196 blocks (one round)
#define QTPB 512   // post: 128 nodes/block -> 391 blocks at 2/CU (one round)
#define LPAD 136   // shorts per LDS row (272 B, 16B-aligned stride)
#define CAP 48     // per-node edge bucket capacity (Poisson(12): P(>=48)~1e-15)

using frag_ab = __attribute__((ext_vector_type(8))) short;  // 8 bf16
using f32x4   = __attribute__((ext_vector_type(4))) float;  // 4 fp32 acc
using u16x4   = __attribute__((ext_vector_type(4))) ushort; // 4 bf16 (8B)

__device__ inline ushort f2b(float f) {
    uint u = __builtin_bit_cast(uint, f);
    u = (u + 0x7FFFu + ((u >> 16) & 1u)) >> 16;
    return (ushort)u;
}
__device__ inline float b2f_lo(uint u) { return __builtin_bit_cast(float, u << 16); }
__device__ inline float b2f_hi(uint u) { return __builtin_bit_cast(float, u & 0xFFFF0000u); }

// ---------------------------------------------------------------------------
// pack: fp32 [128][128] weight -> bf16 fragment order (A-operand of swapped
// product) + zero the degree counters.
// ---------------------------------------------------------------------------
__global__ __launch_bounds__(TPB) void pack_kernel(
    const float* __restrict__ h_w1, const float* __restrict__ f_w,
    const float* __restrict__ g_w1, const float* __restrict__ g_w2,
    short* __restrict__ W1pk, short* __restrict__ Wfpk,
    short* __restrict__ G1pk, short* __restrict__ G2pk,
    int* __restrict__ deg, int M)
{
    int m   = blockIdx.y;
    int fid = blockIdx.x * TPB + threadIdx.x;     // 0..2047
    int lane = fid & 63, ks = (fid >> 6) & 3, nt = fid >> 8;
    const float* src; short* dst; int rowoff = 0;
    if      (m == 0) { src = h_w1; dst = W1pk; }
    else if (m == 1) { src = f_w;  dst = Wfpk; rowoff = 3; }
    else if (m == 2) { src = g_w1; dst = G1pk; }
    else             { src = g_w2; dst = G2pk; }
    int col   = nt * 16 + (lane & 15);
    int kbase = ks * 32 + ((lane >> 4) << 3);
    frag_ab f;
#pragma unroll
    for (int j = 0; j < 8; ++j)
        f[j] = (short)f2b(src[(size_t)(rowoff + kbase + j) * 128 + col]);
    *(frag_ab*)(dst + (((size_t)(nt * 4 + ks) * 64 + lane) << 3)) = f;

    // zero deg: grid-stride
    int flat = (blockIdx.y * gridDim.x + blockIdx.x) * TPB + threadIdx.x;
    int nthr = gridDim.y * gridDim.x * TPB;
    for (int i = flat; i < M; i += nthr) deg[i] = 0;
}

// ---------------------------------------------------------------------------
// prehist: node phase + split padded-bucket scatter: ei loads issued EARLY
// (latency hides under staging+MFMA), atomic+store chains at the very END.
// 1024 threads, 256 nodes/block -> 196 blocks, one round.
// ---------------------------------------------------------------------------
__global__ __launch_bounds__(PTPB) void prehist_kernel(
    const float* __restrict__ x, const float* __restrict__ pos,
    const short* __restrict__ W1pk,   // Wfpk contiguous at +16384
    const float* __restrict__ h_b1,
    const float* __restrict__ h_w2, const float* __restrict__ h_b2,
    const float* __restrict__ f_w, const float* __restrict__ f_b,
    ushort* __restrict__ A2h, ushort* __restrict__ Bvh,
    const int* __restrict__ ei, int* __restrict__ deg,
    int* __restrict__ sspad, int M, int E, int echunk)
{
    __shared__ short wlds[32768];     // 64 KB: W1pk | Wfpk
    const int tid  = threadIdx.x;
    const int lane = tid & 63;
    const int wave = tid >> 6;        // 0..15
    const int kg   = lane >> 4;
    const int node = blockIdx.x * 256 + wave * 16 + (lane & 15);
    const int nc   = node < M ? node : M - 1;

    // issue x + pos loads first (longest latency)
    float4 xv0[4], xv1[4];
#pragma unroll
    for (int ks = 0; ks < 4; ++ks) {
        const float* px = x + (size_t)nc * 128 + ks * 32 + kg * 8;
        xv0[ks] = *(const float4*)px;
        xv1[ks] = *(const float4*)(px + 4);
    }
    float p0 = pos[(size_t)nc * 3 + 0];
    float p1 = pos[(size_t)nc * 3 + 1];
    float p2 = pos[(size_t)nc * 3 + 2];

    // issue ei pair loads EARLY (echunk <= 3*PTPB); values consumed at end
    const int base = blockIdx.x * echunk;
    int end = base + echunk; if (end > E) end = E;
    int esrc[3], edst[3];
    bool ev[3];
#pragma unroll
    for (int t = 0; t < 3; ++t) {
        int i = base + tid + t * PTPB;
        ev[t] = (i < end);
        int ic = ev[t] ? i : base;
        esrc[t] = ei[ic];
        edst[t] = ei[E + ic];
    }

    // stage both weight matrices (contiguous): 4096 int4s / 1024 thr
#pragma unroll
    for (int i = 0; i < 4; ++i) {
        int id = i * PTPB + tid;
        *(int4*)(wlds + (size_t)id * 8) = *(const int4*)(W1pk + (size_t)id * 8);
    }

    // convert x to bf16 fragments while staging lands
    frag_ab xb[4];
#pragma unroll
    for (int ks = 0; ks < 4; ++ks) {
        frag_ab f;
        f[0] = (short)f2b(xv0[ks].x); f[1] = (short)f2b(xv0[ks].y);
        f[2] = (short)f2b(xv0[ks].z); f[3] = (short)f2b(xv0[ks].w);
        f[4] = (short)f2b(xv1[ks].x); f[5] = (short)f2b(xv1[ks].y);
        f[6] = (short)f2b(xv1[ks].z); f[7] = (short)f2b(xv1[ks].w);
        xb[ks] = f;
    }
    __syncthreads();

    f32x4 acch[8], acca[8];
#pragma unroll
    for (int nt = 0; nt < 8; ++nt) { acch[nt] = (f32x4)0.f; acca[nt] = (f32x4)0.f; }
#pragma unroll
    for (int ks = 0; ks < 4; ++ks) {
#pragma unroll
        for (int nt = 0; nt < 8; ++nt) {
            frag_ab wh = *(const frag_ab*)(wlds + (((nt * 4 + ks) * 64 + lane) << 3));
            acch[nt] = __builtin_amdgcn_mfma_f32_16x16x32_bf16(wh, xb[ks], acch[nt], 0, 0, 0);
            frag_ab wf = *(const frag_ab*)(wlds + 16384 + (((nt * 4 + ks) * 64 + lane) << 3));
            acca[nt] = __builtin_amdgcn_mfma_f32_16x16x32_bf16(wf, xb[ks], acca[nt], 0, 0, 0);
        }
    }

    // delta head
    float d0 = 0.f, d1 = 0.f, d2 = 0.f;
#pragma unroll
    for (int nt = 0; nt < 8; ++nt) {
        int f0 = nt * 16 + kg * 4;
        float4 b1 = *(const float4*)(h_b1 + f0);
        float w2[12];
        *(float4*)(w2 + 0) = *(const float4*)(h_w2 + f0 * 3);
        *(float4*)(w2 + 4) = *(const float4*)(h_w2 + f0 * 3 + 4);
        *(float4*)(w2 + 8) = *(const float4*)(h_w2 + f0 * 3 + 8);
#pragma unroll
        for (int j = 0; j < 4; ++j) {
            float h = fmaxf(acch[nt][j] + ((const float*)&b1)[j], 0.f);
            d0 += h * w2[j * 3 + 0];
            d1 += h * w2[j * 3 + 1];
            d2 += h * w2[j * 3 + 2];
        }
    }
    d0 += __shfl_xor(d0, 16); d0 += __shfl_xor(d0, 32);
    d1 += __shfl_xor(d1, 16); d1 += __shfl_xor(d1, 32);
    d2 += __shfl_xor(d2, 16); d2 += __shfl_xor(d2, 32);
    d0 = tanhf(d0 + h_b2[0]);
    d1 = tanhf(d1 + h_b2[1]);
    d2 = tanhf(d2 + h_b2[2]);

    if (node < M) {
#pragma unroll
        for (int nt = 0; nt < 8; ++nt) {
            int f0 = nt * 16 + kg * 4;
            float4 w0 = *(const float4*)(f_w + f0);
            float4 w1 = *(const float4*)(f_w + 128 + f0);
            float4 w2 = *(const float4*)(f_w + 256 + f0);
            float4 fb = *(const float4*)(f_b + f0);
            u16x4 av, bv;
#pragma unroll
            for (int j = 0; j < 4; ++j) {
                float ww0 = ((const float*)&w0)[j];
                float ww1 = ((const float*)&w1)[j];
                float ww2 = ((const float*)&w2)[j];
                float pw = p0 * ww0 + p1 * ww1 + p2 * ww2;
                float dw = d0 * ww0 + d1 * ww1 + d2 * ww2;
                av[j] = f2b(acca[nt][j] + pw);
                bv[j] = f2b(((const float*)&fb)[j] + dw - pw);
            }
            *(u16x4*)(A2h + (size_t)node * 128 + f0) = av;
            *(u16x4*)(Bvh + (size_t)node * 128 + f0) = bv;
        }
    }

    // scatter tail: only the atomic->store chains remain (ei already in regs)
#pragma unroll
    for (int t = 0; t < 3; ++t) {
        if (ev[t]) {
            int p = atomicAdd(&deg[edst[t]], 1);
            if (p < CAP) sspad[edst[t] * CAP + p] = esrc[t];
        }
    }
}

// ---------------------------------------------------------------------------
// segmented reduce over padded buckets: one wave per row, TWO 32-lane halves
// process alternate edges (lane owns 4 cols / 8B); __shfl_xor(32) combines.
// (R12 version: single instruction stream, no half-divergence.)
// ---------------------------------------------------------------------------
__global__ __launch_bounds__(TPB) void reduce_kernel(
    const int* __restrict__ deg, const int* __restrict__ sspad,
    const ushort* __restrict__ A2h, const ushort* __restrict__ Bvh,
    ushort* __restrict__ aggr, int M)
{
    int row = blockIdx.x * 4 + (threadIdx.x >> 6);
    if (row >= M) return;
    int lane = threadIdx.x & 63;
    int half = lane >> 5;
    int cl   = (lane & 31) * 4;

    uint2 bu = *(const uint2*)(Bvh + (size_t)row * 128 + cl);
    float b0 = b2f_lo(bu.x), b1 = b2f_hi(bu.x);
    float b2 = b2f_lo(bu.y), b3 = b2f_hi(bu.y);
    float a0 = 0.f, a1 = 0.f, a2 = 0.f, a3 = 0.f;

    const int* bkt = sspad + (size_t)row * CAP;
    int k1 = deg[row]; if (k1 > CAP) k1 = CAP;
    int k  = half;
    for (; k + 2 < k1; k += 4) {           // this half: edges k, k+2
        int s0 = bkt[k], s1 = bkt[k + 2];
        uint2 u0 = *(const uint2*)(A2h + (size_t)s0 * 128 + cl);
        uint2 u1 = *(const uint2*)(A2h + (size_t)s1 * 128 + cl);
        a0 += fmaxf(b2f_lo(u0.x) + b0, 0.f) + fmaxf(b2f_lo(u1.x) + b0, 0.f);
        a1 += fmaxf(b2f_hi(u0.x) + b1, 0.f) + fmaxf(b2f_hi(u1.x) + b1, 0.f);
        a2 += fmaxf(b2f_lo(u0.y) + b2, 0.f) + fmaxf(b2f_lo(u1.y) + b2, 0.f);
        a3 += fmaxf(b2f_hi(u0.y) + b3, 0.f) + fmaxf(b2f_hi(u1.y) + b3, 0.f);
    }
    for (; k < k1; k += 2) {
        uint2 u0 = *(const uint2*)(A2h + (size_t)bkt[k] * 128 + cl);
        a0 += fmaxf(b2f_lo(u0.x) + b0, 0.f);
        a1 += fmaxf(b2f_hi(u0.x) + b1, 0.f);
        a2 += fmaxf(b2f_lo(u0.y) + b2, 0.f);
        a3 += fmaxf(b2f_hi(u0.y) + b3, 0.f);
    }
    // combine halves
    a0 += __shfl_xor(a0, 32);
    a1 += __shfl_xor(a1, 32);
    a2 += __shfl_xor(a2, 32);
    a3 += __shfl_xor(a3, 32);

    if (half == 0) {
        uint2 r;
        r.x = (uint)f2b(a0) | ((uint)f2b(a1) << 16);
        r.y = (uint)f2b(a2) | ((uint)f2b(a3) << 16);
        *(uint2*)(aggr + (size_t)row * 128 + cl) = r;
    }
}

// ---------------------------------------------------------------------------
// post: out = relu(aggr@g_w1+g_b1)@g_w2 + g_b2 + x  via swapped MFMA.
// ---------------------------------------------------------------------------
__global__ __launch_bounds__(QTPB) void post_kernel(
    const float* __restrict__ x, const ushort* __restrict__ aggr,
    const short* __restrict__ G1pk, const float* __restrict__ g_b1,
    const short* __restrict__ G2pk, const float* __restrict__ g_b2,
    float* __restrict__ out, int M)
{
    __shared__ short glds[16384];           // 32 KB staged weight / out-bounce
    __shared__ short bounce[8 * 16 * LPAD]; // 34.8 KB
    const int tid  = threadIdx.x;
    const int lane = tid & 63;
    const int wave = tid >> 6;              // 0..7
    const int kg   = lane >> 4;
    short* ws = bounce + wave * 16 * LPAD;

    const int node = blockIdx.x * 128 + wave * 16 + (lane & 15);
    const int nc   = node < M ? node : M - 1;

    // B-fragments of aggr^T: direct 16B global loads (issue before staging)
    frag_ab ab[4];
#pragma unroll
    for (int ks = 0; ks < 4; ++ks)
        ab[ks] = *(const frag_ab*)(aggr + (size_t)nc * 128 + ks * 32 + kg * 8);

    // stage G1 (2048 int4s / 512 thr = 4 iters)
#pragma unroll
    for (int i = 0; i < 4; ++i) {
        int id = i * QTPB + tid;
        *(int4*)(glds + (size_t)id * 8) = *(const int4*)(G1pk + (size_t)id * 8);
    }
    __syncthreads();

    // GEMM1: hidden2^T
    f32x4 h2[8];
#pragma unroll
    for (int nt = 0; nt < 8; ++nt) h2[nt] = (f32x4)0.f;
#pragma unroll
    for (int ks = 0; ks < 4; ++ks) {
#pragma unroll
        for (int nt = 0; nt < 8; ++nt) {
            frag_ab g = *(const frag_ab*)(glds + (((nt * 4 + ks) * 64 + lane) << 3));
            h2[nt] = __builtin_amdgcn_mfma_f32_16x16x32_bf16(g, ab[ks], h2[nt], 0, 0, 0);
        }
    }
    // relu+bias -> bf16 -> wave-private LDS
#pragma unroll
    for (int nt = 0; nt < 8; ++nt) {
        int f0 = nt * 16 + kg * 4;
        float4 gb = *(const float4*)(g_b1 + f0);
        u16x4 hv;
#pragma unroll
        for (int j = 0; j < 4; ++j)
            hv[j] = f2b(fmaxf(h2[nt][j] + ((const float*)&gb)[j], 0.f));
        *(u16x4*)(ws + (lane & 15) * LPAD + f0) = hv;
    }
    __syncthreads();   // all waves done reading G1

    // stage G2 over the same buffer
#pragma unroll
    for (int i = 0; i < 4; ++i) {
        int id = i * QTPB + tid;
        *(int4*)(glds + (size_t)id * 8) = *(const int4*)(G2pk + (size_t)id * 8);
    }
    __syncthreads();

    // GEMM2: out^T
    f32x4 o[8];
#pragma unroll
    for (int nt = 0; nt < 8; ++nt) o[nt] = (f32x4)0.f;
#pragma unroll
    for (int ks = 0; ks < 4; ++ks) {
        frag_ab bfr = *(const frag_ab*)(ws + (lane & 15) * LPAD + ks * 32 + kg * 8);
#pragma unroll
        for (int nt = 0; nt < 8; ++nt) {
            frag_ab g = *(const frag_ab*)(glds + (((nt * 4 + ks) * 64 + lane) << 3));
            o[nt] = __builtin_amdgcn_mfma_f32_16x16x32_bf16(g, bfr, o[nt], 0, 0, 0);
        }
    }

    __syncthreads();   // all waves done reading G2: glds becomes out-bounce
    float* ob = (float*)glds + (wave << 10);   // 4 KB per wave
    const int nhalf = (lane & 15) >> 3;
#pragma unroll
    for (int p = 0; p < 2; ++p) {
        if (nhalf == p) {
            int ln = lane & 7;
#pragma unroll
            for (int nt = 0; nt < 8; ++nt) {
                float4 v;
                v.x = o[nt][0]; v.y = o[nt][1]; v.z = o[nt][2]; v.w = o[nt][3];
                *(float4*)(ob + ln * 128 + nt * 16 + kg * 4) = v;
            }
        }
#pragma unroll
        for (int it = 0; it < 4; ++it) {
            int ln2 = lane >> 3;           // 0..7
            int cc  = (lane & 7) + it * 8; // 0..31 (16B chunks)
            float4 v = *(const float4*)(ob + ln2 * 128 + cc * 4);
            int gn = blockIdx.x * 128 + wave * 16 + p * 8 + ln2;
            if (gn < M) {
                float4 xv = *(const float4*)(x + (size_t)gn * 128 + cc * 4);
                float4 gb = *(const float4*)(g_b2 + cc * 4);
                float4 ov;
                ov.x = v.x + gb.x + xv.x; ov.y = v.y + gb.y + xv.y;
                ov.z = v.z + gb.z + xv.z; ov.w = v.w + gb.w + xv.w;
                *(float4*)(out + (size_t)gn * 128 + cc * 4) = ov;
            }
        }
    }
}

extern "C" void kernel_launch(void* const* d_in, const int* in_sizes, int n_in,
                              void* d_out, int out_size, void* d_ws, size_t ws_size,
                              hipStream_t stream)
{
    const float* x    = (const float*)d_in[0];
    const float* pos  = (const float*)d_in[1];
    const int*   ei   = (const int*)d_in[2];
    const float* h_w1 = (const float*)d_in[3];
    const float* h_b1 = (const float*)d_in[4];
    const float* h_w2 = (const float*)d_in[5];
    const float* h_b2 = (const float*)d_in[6];
    const float* f_w  = (const float*)d_in[7];
    const float* f_b  = (const float*)d_in[8];
    const float* g_w1 = (const float*)d_in[9];
    const float* g_b1 = (const float*)d_in[10];
    const float* g_w2 = (const float*)d_in[11];
    const float* g_b2 = (const float*)d_in[12];

    const int M = in_sizes[1] / 3;       // 50000
    const int E = in_sizes[2] / 2;       // 600000
    const int nbp = (M + 255) / 256;     // 196 prehist blocks
    const int nbq = (M + 127) / 128;     // 391 post blocks
    const int echunk = (E + nbp - 1) / nbp;   // 3062 <= 3*PTPB

    ushort* A2h  = (ushort*)d_ws;                          // [M][128] bf16
    ushort* Bvh  = A2h + (size_t)M * 128;                  // [M][128] bf16
    ushort* aggr = Bvh + (size_t)M * 128;                  // [M][128] bf16
    short* W1pk  = (short*)(aggr + (size_t)M * 128);       // 16384 each, W1|Wf contiguous
    short* Wfpk  = W1pk + 16384;
    short* G1pk  = Wfpk + 16384;
    short* G2pk  = G1pk + 16384;
    int* deg     = (int*)(G2pk + 16384);                   // [M]
    int* sspad   = deg + M;                                // [M*CAP]
    float* out   = (float*)d_out;

    pack_kernel<<<dim3(8, 4), TPB, 0, stream>>>(h_w1, f_w, g_w1, g_w2,
                                                W1pk, Wfpk, G1pk, G2pk,
                                                deg, M);
    prehist_kernel<<<nbp, PTPB, 0, stream>>>(x, pos, W1pk, h_b1, h_w2, h_b2,
                                             f_w, f_b, A2h, Bvh,
                                             ei, deg, sspad, M, E, echunk);
    reduce_kernel<<<(M + 3) / 4, TPB, 0, stream>>>(deg, sspad, A2h, Bvh, aggr, M);
    post_kernel<<<nbq, QTPB, 0, stream>>>(x, aggr, G1pk, g_b1, G2pk, g_b2, out, M);
}